// Round 5
// baseline (684.545 us; speedup 1.0000x reference)
//
#include <hip/hip_runtime.h>
#include <hip/hip_fp16.h>

typedef _Float16 f16x4 __attribute__((ext_vector_type(4)));
typedef _Float16 f16x8 __attribute__((ext_vector_type(8)));
typedef float    f32x4 __attribute__((ext_vector_type(4)));
typedef float    f32x16 __attribute__((ext_vector_type(16)));

#define TBD 67108864ull   // T*B*D
#define BD  1048576ull    // B*D

#define ASM_VMCNT(N) asm volatile("s_waitcnt vmcnt(" #N ")" ::: "memory")
#define ASM_LGKM(N)  asm volatile("s_waitcnt lgkmcnt(" #N ")" ::: "memory")
#define BARRIER()    __builtin_amdgcn_s_barrier()
#define SCHED0()     __builtin_amdgcn_sched_barrier(0)
#define MFMA32(a,b,c) __builtin_amdgcn_mfma_f32_32x32x16_f16((a),(b),(c),0,0,0)

// ---------------- Kernel 1: se = (pred-true)^2, split into fp16 hi/lo ----------------
__global__ __launch_bounds__(256) void se_split_k(const float* __restrict__ pred,
                                                  const float* __restrict__ tru,
                                                  _Float16* __restrict__ hi,
                                                  _Float16* __restrict__ lo) {
  size_t stride = (size_t)gridDim.x * 1024;
  for (size_t i = ((size_t)blockIdx.x * 256 + threadIdx.x) * 4; i < TBD; i += stride) {
    float4 p = *(const float4*)(pred + i);
    float4 t = *(const float4*)(tru + i);
    float s0 = (p.x - t.x) * (p.x - t.x);
    float s1 = (p.y - t.y) * (p.y - t.y);
    float s2 = (p.z - t.z) * (p.z - t.z);
    float s3 = (p.w - t.w) * (p.w - t.w);
    f16x4 h, l;
    h[0] = (_Float16)s0; l[0] = (_Float16)(s0 - (float)h[0]);
    h[1] = (_Float16)s1; l[1] = (_Float16)(s1 - (float)h[1]);
    h[2] = (_Float16)s2; l[2] = (_Float16)(s2 - (float)h[2]);
    h[3] = (_Float16)s3; l[3] = (_Float16)(s3 - (float)h[3]);
    *(f16x4*)(hi + i) = h;
    *(f16x4*)(lo + i) = l;
  }
}

// ---------------- Kernel 2: split W into fp16 hi/lo ----------------
__global__ __launch_bounds__(256) void w_split_k(const float* __restrict__ W,
                                                 _Float16* __restrict__ hi,
                                                 _Float16* __restrict__ lo) {
  size_t i = ((size_t)blockIdx.x * 256 + threadIdx.x) * 4;  // covers 1048576 exactly
  float4 x = *(const float4*)(W + i);
  f16x4 h, l;
  h[0] = (_Float16)x.x; l[0] = (_Float16)(x.x - (float)h[0]);
  h[1] = (_Float16)x.y; l[1] = (_Float16)(x.y - (float)h[1]);
  h[2] = (_Float16)x.z; l[2] = (_Float16)(x.z - (float)h[2]);
  h[3] = (_Float16)x.w; l[3] = (_Float16)(x.w - (float)h[3]);
  *(f16x4*)(hi + i) = h;
  *(f16x4*)(lo + i) = l;
}

// ---------------- Kernel 3: logits = SE @ W^T + b (split-fp16 3-pass, 32x32 MFMA) -----
// M=65536, N=1024, K=1024. Tile 128x128, BK=32, 4 waves (2M x 2N), per-wave 64x64.
// 2 blocks/CU (64 KiB LDS, 256 thr): independent barrier domains overlap ds_read
// phases of one block with MFMA phases of the other (round-4 lesson: single-block
// lockstep serializes LDS reads with MFMA).
// LDS: 2 buffers x 32KB; buffer = A[128 rows][128B] + B[128 rows][128B].
// Row = 8 x 16B slots: hi k0..31 in slots 0-3, lo in 4-7; physical slot = logical ^ (row&7).
// Per tile: 2 k-step phases; stage next+1 tile inside phase 1 after all-reads barrier;
// counted vmcnt(8), never drained in main loop.

#define STAGE8(kof, dst)                                                         \
  _Pragma("unroll")                                                              \
  for (int q = 0; q < 4; ++q) {                                                  \
    __builtin_amdgcn_global_load_lds(                                            \
        (const __attribute__((address_space(1))) void*)(aSrc[q] + (kof)),        \
        (__attribute__((address_space(3))) void*)((dst) + q * 4096 + tid * 16),  \
        16, 0, 0);                                                               \
    __builtin_amdgcn_global_load_lds(                                            \
        (const __attribute__((address_space(1))) void*)(bSrc[q] + (kof)),        \
        (__attribute__((address_space(3))) void*)((dst) + 16384 + q * 4096 + tid * 16), \
        16, 0, 0);                                                               \
  }

// 12 MFMAs: pass-major (HH, LH, HL), 4 independent accumulators per pass.
#define MFMA_CL(AH0, AL0, AH1, AL1, BH0, BL0, BH1, BL1)          \
  __builtin_amdgcn_s_setprio(1);                                 \
  acc[0][0] = MFMA32(AH0, BH0, acc[0][0]);                       \
  acc[0][1] = MFMA32(AH0, BH1, acc[0][1]);                       \
  acc[1][0] = MFMA32(AH1, BH0, acc[1][0]);                       \
  acc[1][1] = MFMA32(AH1, BH1, acc[1][1]);                       \
  acc[0][0] = MFMA32(AL0, BH0, acc[0][0]);                       \
  acc[0][1] = MFMA32(AL0, BH1, acc[0][1]);                       \
  acc[1][0] = MFMA32(AL1, BH0, acc[1][0]);                       \
  acc[1][1] = MFMA32(AL1, BH1, acc[1][1]);                       \
  acc[0][0] = MFMA32(AH0, BL0, acc[0][0]);                       \
  acc[0][1] = MFMA32(AH0, BL1, acc[0][1]);                       \
  acc[1][0] = MFMA32(AH1, BL0, acc[1][0]);                       \
  acc[1][1] = MFMA32(AH1, BL1, acc[1][1]);                       \
  __builtin_amdgcn_s_setprio(0);

__global__ __launch_bounds__(256, 2) void gemm_logits_k(
    const _Float16* __restrict__ Ah, const _Float16* __restrict__ Al,
    const _Float16* __restrict__ Wh, const _Float16* __restrict__ Wl,
    const float* __restrict__ bias, float* __restrict__ C) {
  __shared__ uint4 lds4[4096];  // 64 KiB
  char* lds = (char*)lds4;
  const int tid = threadIdx.x;
  const int lane = tid & 63;
  const int wid = tid >> 6;          // 0..3
  const int wm = wid >> 1;           // 0..1 (M)
  const int wn = wid & 1;            // 0..1 (N)

  // XCD-aware bijective swizzle: 4096 blocks, 8 XCDs, 512 per XCD.
  const int bid = blockIdx.x;
  const int wgid = (bid & 7) * 512 + (bid >> 3);
  const int bm = wgid >> 3, bn = wgid & 7;   // 512 M-tiles x 8 N-tiles
  const int row0 = bm * 128, col0 = bn * 128;

  // Staging source addresses (inverse-swizzled), 4 A + 4 B chunks of 16B per thread.
  const _Float16* aSrc[4];
  const _Float16* bSrc[4];
#pragma unroll
  for (int q = 0; q < 4; ++q) {
    int p = q * 4096 + tid * 16;      // byte offset in 16KB region
    int r = p >> 7;                   // row 0..127
    int s = (p >> 4) & 7;             // physical slot
    int sig = s ^ (r & 7);            // logical slot
    size_t koff = (size_t)(sig & 3) * 8;
    aSrc[q] = (sig < 4 ? Ah : Al) + ((size_t)(row0 + r) * 1024 + koff);
    bSrc[q] = (sig < 4 ? Wh : Wl) + ((size_t)(col0 + r) * 1024 + koff);
  }

  // Fragment read offsets. 32x32x16 A-operand: lane l -> row l&31, k = 8*(l>>5)+e.
  const int l31 = lane & 31;
  const int u5 = lane >> 5;          // 0..1
  const int aRow0 = wm * 64 + l31;         // fi=0 row
  const int aRow1 = wm * 64 + 32 + l31;    // fi=1 row
  const int bRow0 = wn * 64 + l31;
  const int bRow1 = wn * 64 + 32 + l31;
  // byte offset builder: row*128 + ((logical_slot) ^ (row&7))*16 ; logical hi = 2*ks+u5, lo = +4
#define AOFF(row, ks, lo) ((row) * 128 + (((2 * (ks) + u5 + ((lo) ? 4 : 0)) ^ ((row) & 7)) * 16))
#define BOFF(row, ks, lo) (16384 + (row) * 128 + (((2 * (ks) + u5 + ((lo) ? 4 : 0)) ^ ((row) & 7)) * 16))

  f32x16 acc[2][2] = {};

  // Prologue: stage tile 0 -> buf0, tile 1 -> buf1; wait tile 0 (tile 1 in flight).
  STAGE8(0, lds)
  STAGE8(32, lds + 32768)
  ASM_VMCNT(8);
  BARRIER();

#pragma unroll 1
  for (int t = 0; t < 32; ++t) {
    char* ldsb = lds + (t & 1) * 32768;
    const int tt = (t + 2 < 32) ? t + 2 : 31;   // dummy tail reload keeps vmcnt uniform
    const size_t kof = (size_t)tt * 32;

    // ---- phase 0: k-step 0 ----
    f16x8 a0h = *(const f16x8*)(ldsb + AOFF(aRow0, 0, 0));
    f16x8 a0l = *(const f16x8*)(ldsb + AOFF(aRow0, 0, 1));
    f16x8 a1h = *(const f16x8*)(ldsb + AOFF(aRow1, 0, 0));
    f16x8 a1l = *(const f16x8*)(ldsb + AOFF(aRow1, 0, 1));
    f16x8 b0h = *(const f16x8*)(ldsb + BOFF(bRow0, 0, 0));
    f16x8 b0l = *(const f16x8*)(ldsb + BOFF(bRow0, 0, 1));
    f16x8 b1h = *(const f16x8*)(ldsb + BOFF(bRow1, 0, 0));
    f16x8 b1l = *(const f16x8*)(ldsb + BOFF(bRow1, 0, 1));
    ASM_LGKM(0);
    SCHED0();
    MFMA_CL(a0h, a0l, a1h, a1l, b0h, b0l, b1h, b1l)

    // ---- phase 1: k-step 1 (same buffer, no barrier needed before reads) ----
    f16x8 c0h = *(const f16x8*)(ldsb + AOFF(aRow0, 1, 0));
    f16x8 c0l = *(const f16x8*)(ldsb + AOFF(aRow0, 1, 1));
    f16x8 c1h = *(const f16x8*)(ldsb + AOFF(aRow1, 1, 0));
    f16x8 c1l = *(const f16x8*)(ldsb + AOFF(aRow1, 1, 1));
    f16x8 d0h = *(const f16x8*)(ldsb + BOFF(bRow0, 1, 0));
    f16x8 d0l = *(const f16x8*)(ldsb + BOFF(bRow0, 1, 1));
    f16x8 d1h = *(const f16x8*)(ldsb + BOFF(bRow1, 1, 0));
    f16x8 d1l = *(const f16x8*)(ldsb + BOFF(bRow1, 1, 1));
    ASM_LGKM(0);
    SCHED0();
    BARRIER();                 // all waves done reading ldsb -> safe to overwrite
    STAGE8(kof, ldsb)          // stage tile t+2 into this buffer
    SCHED0();
    MFMA_CL(c0h, c0l, c1h, c1l, d0h, d0l, d1h, d1l)
    ASM_VMCNT(8);              // tile t+1's 8 loads landed (t+2's 8 in flight)
    BARRIER();
  }
  ASM_VMCNT(0);    // drain tail dummy loads

  // Epilogue: 32x32 C/D mapping: col = lane&31, row = (reg&3) + 8*(reg>>2) + 4*(lane>>5).
#pragma unroll
  for (int fj = 0; fj < 2; ++fj) {
    int c = col0 + wn * 64 + fj * 32 + l31;
    float bj = bias[c];
#pragma unroll
    for (int fi = 0; fi < 2; ++fi) {
      int rbase = row0 + wm * 64 + fi * 32 + 4 * u5;
#pragma unroll
      for (int reg = 0; reg < 16; ++reg) {
        int r = rbase + (reg & 3) + 8 * (reg >> 2);
        C[(size_t)r * 1024 + c] = acc[fi][fj][reg] + bj;
      }
    }
  }
}

// ---------------- Kernel 4: fused softmax + gating + loss accumulation ----------------
__global__ __launch_bounds__(256) void softmax_loss_k(const float* __restrict__ logits,
                                                      const _Float16* __restrict__ hi,
                                                      const _Float16* __restrict__ lo,
                                                      float* __restrict__ out) {
  const int b = blockIdx.x;            // 0..1023
  const int tid = threadIdx.x, lane = tid & 63, wid = tid >> 6;
  __shared__ float red[8];
  float4 wprev = make_float4(1.f, 1.f, 1.f, 1.f);
  float4 lacc  = make_float4(0.f, 0.f, 0.f, 0.f);

  size_t base = (size_t)b * 1024;      // row (t=0, b)
  float4 x = ((const float4*)(logits + base))[tid];
  f16x4  h = ((const f16x4*)(hi + base))[tid];
  f16x4  l = ((const f16x4*)(lo + base))[tid];

#pragma unroll 1
  for (int t = 0; t < 64; ++t) {
    float4 se;
    se.x = (float)h[0] + (float)l[0];
    se.y = (float)h[1] + (float)l[1];
    se.z = (float)h[2] + (float)l[2];
    se.w = (float)h[3] + (float)l[3];
    lacc.x += wprev.x * se.x;
    lacc.y += wprev.y * se.y;
    lacc.z += wprev.z * se.z;
    lacc.w += wprev.w * se.w;

    int tn = (t + 1 < 64) ? t + 1 : t;
    size_t nbase = ((size_t)tn * 1024 + (size_t)b) * 1024;
    float4 xn = ((const float4*)(logits + nbase))[tid];
    f16x4  hn = ((const f16x4*)(hi + nbase))[tid];
    f16x4  ln = ((const f16x4*)(lo + nbase))[tid];

    float m = fmaxf(fmaxf(x.x, x.y), fmaxf(x.z, x.w));
#pragma unroll
    for (int o = 32; o >= 1; o >>= 1) m = fmaxf(m, __shfl_xor(m, o, 64));
    if (lane == 0) red[wid] = m;
    __syncthreads();
    m = fmaxf(fmaxf(red[0], red[1]), fmaxf(red[2], red[3]));
    float e0 = __expf(x.x - m), e1 = __expf(x.y - m), e2 = __expf(x.z - m), e3 = __expf(x.w - m);
    float s = (e0 + e1) + (e2 + e3);
#pragma unroll
    for (int o = 32; o >= 1; o >>= 1) s += __shfl_xor(s, o, 64);
    if (lane == 0) red[4 + wid] = s;
    __syncthreads();
    s = (red[4] + red[5]) + (red[6] + red[7]);
    float inv = 1.0f / s;

    wprev.x = se.x * e0 * inv;
    wprev.y = se.y * e1 * inv;
    wprev.z = se.z * e2 * inv;
    wprev.w = se.w * e3 * inv;

    x = xn; h = hn; l = ln;
  }
  ((float4*)(out + (size_t)b * 1024))[tid] = lacc;
}

extern "C" void kernel_launch(void* const* d_in, const int* in_sizes, int n_in,
                              void* d_out, int out_size, void* d_ws, size_t ws_size,
                              hipStream_t stream) {
  const float* pred = (const float*)d_in[0];
  const float* tru  = (const float*)d_in[1];
  const float* W    = (const float*)d_in[2];
  const float* bias = (const float*)d_in[3];
  float* out = (float*)d_out;

  char* ws = (char*)d_ws;
  _Float16* se_hi  = (_Float16*)(ws);                    // 128 MB
  _Float16* se_lo  = (_Float16*)(ws + 134217728ull);     // 128 MB
  float*    logits = (float*)   (ws + 268435456ull);     // 256 MB
  _Float16* W_hi   = (_Float16*)(ws + 536870912ull);     // 2 MB
  _Float16* W_lo   = (_Float16*)(ws + 538968064ull);     // 2 MB

  se_split_k<<<2048, 256, 0, stream>>>(pred, tru, se_hi, se_lo);
  w_split_k<<<1024, 256, 0, stream>>>(W, W_hi, W_lo);
  gemm_logits_k<<<4096, 256, 0, stream>>>(se_hi, se_lo, W_hi, W_lo, bias, logits);
  softmax_loss_k<<<1024, 256, 0, stream>>>(logits, se_hi, se_lo, out);
}

// Round 6
// 682.816 us; speedup vs baseline: 1.0025x; 1.0025x over previous
//
#include <hip/hip_runtime.h>
#include <hip/hip_fp16.h>

typedef _Float16 f16x4 __attribute__((ext_vector_type(4)));
typedef _Float16 f16x8 __attribute__((ext_vector_type(8)));
typedef float    f32x4 __attribute__((ext_vector_type(4)));
typedef float    f32x16 __attribute__((ext_vector_type(16)));

#define TBD 67108864ull   // T*B*D
#define BD  1048576ull    // B*D

#define ASM_VMCNT(N) asm volatile("s_waitcnt vmcnt(" #N ")" ::: "memory")
#define ASM_LGKM(N)  asm volatile("s_waitcnt lgkmcnt(" #N ")" ::: "memory")
#define BARRIER()    __builtin_amdgcn_s_barrier()
#define SCHED0()     __builtin_amdgcn_sched_barrier(0)
#define MFMA32(a,b,c) __builtin_amdgcn_mfma_f32_32x32x16_f16((a),(b),(c),0,0,0)

// ---------------- Kernel 1: se = (pred-true)^2, split into fp16 hi/lo ----------------
__global__ __launch_bounds__(256) void se_split_k(const float* __restrict__ pred,
                                                  const float* __restrict__ tru,
                                                  _Float16* __restrict__ hi,
                                                  _Float16* __restrict__ lo) {
  size_t stride = (size_t)gridDim.x * 1024;
  for (size_t i = ((size_t)blockIdx.x * 256 + threadIdx.x) * 4; i < TBD; i += stride) {
    float4 p = *(const float4*)(pred + i);
    float4 t = *(const float4*)(tru + i);
    float s0 = (p.x - t.x) * (p.x - t.x);
    float s1 = (p.y - t.y) * (p.y - t.y);
    float s2 = (p.z - t.z) * (p.z - t.z);
    float s3 = (p.w - t.w) * (p.w - t.w);
    f16x4 h, l;
    h[0] = (_Float16)s0; l[0] = (_Float16)(s0 - (float)h[0]);
    h[1] = (_Float16)s1; l[1] = (_Float16)(s1 - (float)h[1]);
    h[2] = (_Float16)s2; l[2] = (_Float16)(s2 - (float)h[2]);
    h[3] = (_Float16)s3; l[3] = (_Float16)(s3 - (float)h[3]);
    *(f16x4*)(hi + i) = h;
    *(f16x4*)(lo + i) = l;
  }
}

// ---------------- Kernel 2: split W into fp16 hi/lo ----------------
__global__ __launch_bounds__(256) void w_split_k(const float* __restrict__ W,
                                                 _Float16* __restrict__ hi,
                                                 _Float16* __restrict__ lo) {
  size_t i = ((size_t)blockIdx.x * 256 + threadIdx.x) * 4;  // covers 1048576 exactly
  float4 x = *(const float4*)(W + i);
  f16x4 h, l;
  h[0] = (_Float16)x.x; l[0] = (_Float16)(x.x - (float)h[0]);
  h[1] = (_Float16)x.y; l[1] = (_Float16)(x.y - (float)h[1]);
  h[2] = (_Float16)x.z; l[2] = (_Float16)(x.z - (float)h[2]);
  h[3] = (_Float16)x.w; l[3] = (_Float16)(x.w - (float)h[3]);
  *(f16x4*)(hi + i) = h;
  *(f16x4*)(lo + i) = l;
}

// ---------------- Kernel 3: logits = SE @ W^T + b (split-fp16 3-pass, 32x32 MFMA) -----
// M=65536, N=1024, K=1024. Tile 128x128, BK=32, 4 waves (2M x 2N), per-wave 64x64.
// 2 blocks/CU (64 KiB LDS): independent barrier domains overlap LDS phases of one
// block with MFMA phases of the other.
// LDS: 2 buffers x 32KB; buffer = A[128 rows][128B] + B[128 rows][128B].
// Row = 8 x 16B slots; physical slot = logical ^ (row&7) ^ ((row>>3)&3).
//   (round-5 lesson: conflict groups are strided lanes {l, l+8,...}; the extra
//    (row>>3)&3 term makes rows r,r+8,r+16,r+24 land on distinct banks -> 2-way max.)
// Per tile: both k-steps' reads issued up front; lgkm(8)/lgkm(0) fences;
// stage next+1 tile after the all-reads barrier; counted vmcnt(8), never drained.

#define STAGE8(kof, dst)                                                         \
  _Pragma("unroll")                                                              \
  for (int q = 0; q < 4; ++q) {                                                  \
    __builtin_amdgcn_global_load_lds(                                            \
        (const __attribute__((address_space(1))) void*)(aSrc[q] + (kof)),        \
        (__attribute__((address_space(3))) void*)((dst) + q * 4096 + tid * 16),  \
        16, 0, 0);                                                               \
    __builtin_amdgcn_global_load_lds(                                            \
        (const __attribute__((address_space(1))) void*)(bSrc[q] + (kof)),        \
        (__attribute__((address_space(3))) void*)((dst) + 16384 + q * 4096 + tid * 16), \
        16, 0, 0);                                                               \
  }

// 12 MFMAs: pass-major (HH, LH, HL), 4 independent accumulators per pass.
#define MFMA_CL(AH0, AL0, AH1, AL1, BH0, BL0, BH1, BL1)          \
  __builtin_amdgcn_s_setprio(1);                                 \
  acc[0][0] = MFMA32(AH0, BH0, acc[0][0]);                       \
  acc[0][1] = MFMA32(AH0, BH1, acc[0][1]);                       \
  acc[1][0] = MFMA32(AH1, BH0, acc[1][0]);                       \
  acc[1][1] = MFMA32(AH1, BH1, acc[1][1]);                       \
  acc[0][0] = MFMA32(AL0, BH0, acc[0][0]);                       \
  acc[0][1] = MFMA32(AL0, BH1, acc[0][1]);                       \
  acc[1][0] = MFMA32(AL1, BH0, acc[1][0]);                       \
  acc[1][1] = MFMA32(AL1, BH1, acc[1][1]);                       \
  acc[0][0] = MFMA32(AH0, BL0, acc[0][0]);                       \
  acc[0][1] = MFMA32(AH0, BL1, acc[0][1]);                       \
  acc[1][0] = MFMA32(AH1, BL0, acc[1][0]);                       \
  acc[1][1] = MFMA32(AH1, BL1, acc[1][1]);                       \
  __builtin_amdgcn_s_setprio(0);

__global__ __launch_bounds__(256, 2) void gemm_logits_k(
    const _Float16* __restrict__ Ah, const _Float16* __restrict__ Al,
    const _Float16* __restrict__ Wh, const _Float16* __restrict__ Wl,
    const float* __restrict__ bias, float* __restrict__ C) {
  __shared__ uint4 lds4[4096];  // 64 KiB
  char* lds = (char*)lds4;
  const int tid = threadIdx.x;
  const int lane = tid & 63;
  const int wid = tid >> 6;          // 0..3
  const int wm = wid >> 1;           // 0..1 (M)
  const int wn = wid & 1;            // 0..1 (N)

  // XCD-aware bijective swizzle: 4096 blocks, 8 XCDs, 512 per XCD.
  const int bid = blockIdx.x;
  const int wgid = (bid & 7) * 512 + (bid >> 3);
  const int bm = wgid >> 3, bn = wgid & 7;   // 512 M-tiles x 8 N-tiles
  const int row0 = bm * 128, col0 = bn * 128;

  // Staging source addresses (inverse-swizzled), 4 A + 4 B chunks of 16B per thread.
  const _Float16* aSrc[4];
  const _Float16* bSrc[4];
#pragma unroll
  for (int q = 0; q < 4; ++q) {
    int p = q * 4096 + tid * 16;      // byte offset in 16KB region
    int r = p >> 7;                   // row 0..127
    int s = (p >> 4) & 7;             // physical slot
    int sig = s ^ (r & 7) ^ ((r >> 3) & 3);  // logical slot (involution)
    size_t koff = (size_t)(sig & 3) * 8;
    aSrc[q] = (sig < 4 ? Ah : Al) + ((size_t)(row0 + r) * 1024 + koff);
    bSrc[q] = (sig < 4 ? Wh : Wl) + ((size_t)(col0 + r) * 1024 + koff);
  }

  // Fragment read offsets. 32x32x16 A-operand: lane l -> row l&31, k = 8*(l>>5)+e.
  const int l31 = lane & 31;
  const int u5 = lane >> 5;          // 0..1
  const int aRow0 = wm * 64 + l31;         // fi=0 row
  const int aRow1 = wm * 64 + 32 + l31;    // fi=1 row
  const int bRow0 = wn * 64 + l31;
  const int bRow1 = wn * 64 + 32 + l31;
  // byte offset: row*128 + ((ls ^ (row&7) ^ ((row>>3)&3)) * 16), ls = 2*ks+u5 (+4 for lo)
#define SWZ(row, ls) (((ls) ^ ((row) & 7) ^ (((row) >> 3) & 3)) * 16)
#define AOFF(row, ks, lo) ((row) * 128 + SWZ(row, 2 * (ks) + u5 + ((lo) ? 4 : 0)))
#define BOFF(row, ks, lo) (16384 + (row) * 128 + SWZ(row, 2 * (ks) + u5 + ((lo) ? 4 : 0)))

  f32x16 acc[2][2] = {};

  // Prologue: stage tile 0 -> buf0, tile 1 -> buf1; wait tile 0 (tile 1 in flight).
  STAGE8(0, lds)
  STAGE8(32, lds + 32768)
  ASM_VMCNT(8);
  BARRIER();

#pragma unroll 1
  for (int t = 0; t < 32; ++t) {
    char* ldsb = lds + (t & 1) * 32768;
    const int tt = (t + 2 < 32) ? t + 2 : 31;   // dummy tail reload keeps vmcnt uniform
    const size_t kof = (size_t)tt * 32;

    // ---- issue ALL 16 reads (both k-steps) up front ----
    f16x8 a0h = *(const f16x8*)(ldsb + AOFF(aRow0, 0, 0));
    f16x8 a0l = *(const f16x8*)(ldsb + AOFF(aRow0, 0, 1));
    f16x8 a1h = *(const f16x8*)(ldsb + AOFF(aRow1, 0, 0));
    f16x8 a1l = *(const f16x8*)(ldsb + AOFF(aRow1, 0, 1));
    f16x8 b0h = *(const f16x8*)(ldsb + BOFF(bRow0, 0, 0));
    f16x8 b0l = *(const f16x8*)(ldsb + BOFF(bRow0, 0, 1));
    f16x8 b1h = *(const f16x8*)(ldsb + BOFF(bRow1, 0, 0));
    f16x8 b1l = *(const f16x8*)(ldsb + BOFF(bRow1, 0, 1));
    f16x8 c0h = *(const f16x8*)(ldsb + AOFF(aRow0, 1, 0));
    f16x8 c0l = *(const f16x8*)(ldsb + AOFF(aRow0, 1, 1));
    f16x8 c1h = *(const f16x8*)(ldsb + AOFF(aRow1, 1, 0));
    f16x8 c1l = *(const f16x8*)(ldsb + AOFF(aRow1, 1, 1));
    f16x8 d0h = *(const f16x8*)(ldsb + BOFF(bRow0, 1, 0));
    f16x8 d0l = *(const f16x8*)(ldsb + BOFF(bRow0, 1, 1));
    f16x8 d1h = *(const f16x8*)(ldsb + BOFF(bRow1, 1, 0));
    f16x8 d1l = *(const f16x8*)(ldsb + BOFF(bRow1, 1, 1));
    ASM_LGKM(8);               // k-step-0 octet resident (k-step-1 in flight)
    SCHED0();
    MFMA_CL(a0h, a0l, a1h, a1l, b0h, b0l, b1h, b1l)
    ASM_LGKM(0);               // k-step-1 octet resident
    SCHED0();
    BARRIER();                 // all waves done reading ldsb -> safe to overwrite
    STAGE8(kof, ldsb)          // stage tile t+2 into this buffer
    SCHED0();
    MFMA_CL(c0h, c0l, c1h, c1l, d0h, d0l, d1h, d1l)
    ASM_VMCNT(8);              // tile t+1's 8 loads landed (t+2's 8 in flight)
    BARRIER();
  }
  ASM_VMCNT(0);    // drain tail dummy loads

  // Epilogue: 32x32 C/D mapping: col = lane&31, row = (reg&3) + 8*(reg>>2) + 4*(lane>>5).
#pragma unroll
  for (int fj = 0; fj < 2; ++fj) {
    int c = col0 + wn * 64 + fj * 32 + l31;
    float bj = bias[c];
#pragma unroll
    for (int fi = 0; fi < 2; ++fi) {
      int rbase = row0 + wm * 64 + fi * 32 + 4 * u5;
#pragma unroll
      for (int reg = 0; reg < 16; ++reg) {
        int r = rbase + (reg & 3) + 8 * (reg >> 2);
        C[(size_t)r * 1024 + c] = acc[fi][fj][reg] + bj;
      }
    }
  }
}

// ---------------- Kernel 4: fused softmax + gating + loss accumulation ----------------
__global__ __launch_bounds__(256) void softmax_loss_k(const float* __restrict__ logits,
                                                      const _Float16* __restrict__ hi,
                                                      const _Float16* __restrict__ lo,
                                                      float* __restrict__ out) {
  const int b = blockIdx.x;            // 0..1023
  const int tid = threadIdx.x, lane = tid & 63, wid = tid >> 6;
  __shared__ float red[8];
  float4 wprev = make_float4(1.f, 1.f, 1.f, 1.f);
  float4 lacc  = make_float4(0.f, 0.f, 0.f, 0.f);

  size_t base = (size_t)b * 1024;      // row (t=0, b)
  float4 x = ((const float4*)(logits + base))[tid];
  f16x4  h = ((const f16x4*)(hi + base))[tid];
  f16x4  l = ((const f16x4*)(lo + base))[tid];

#pragma unroll 1
  for (int t = 0; t < 64; ++t) {
    float4 se;
    se.x = (float)h[0] + (float)l[0];
    se.y = (float)h[1] + (float)l[1];
    se.z = (float)h[2] + (float)l[2];
    se.w = (float)h[3] + (float)l[3];
    lacc.x += wprev.x * se.x;
    lacc.y += wprev.y * se.y;
    lacc.z += wprev.z * se.z;
    lacc.w += wprev.w * se.w;

    int tn = (t + 1 < 64) ? t + 1 : t;
    size_t nbase = ((size_t)tn * 1024 + (size_t)b) * 1024;
    float4 xn = ((const float4*)(logits + nbase))[tid];
    f16x4  hn = ((const f16x4*)(hi + nbase))[tid];
    f16x4  ln = ((const f16x4*)(lo + nbase))[tid];

    float m = fmaxf(fmaxf(x.x, x.y), fmaxf(x.z, x.w));
#pragma unroll
    for (int o = 32; o >= 1; o >>= 1) m = fmaxf(m, __shfl_xor(m, o, 64));
    if (lane == 0) red[wid] = m;
    __syncthreads();
    m = fmaxf(fmaxf(red[0], red[1]), fmaxf(red[2], red[3]));
    float e0 = __expf(x.x - m), e1 = __expf(x.y - m), e2 = __expf(x.z - m), e3 = __expf(x.w - m);
    float s = (e0 + e1) + (e2 + e3);
#pragma unroll
    for (int o = 32; o >= 1; o >>= 1) s += __shfl_xor(s, o, 64);
    if (lane == 0) red[4 + wid] = s;
    __syncthreads();
    s = (red[4] + red[5]) + (red[6] + red[7]);
    float inv = 1.0f / s;

    wprev.x = se.x * e0 * inv;
    wprev.y = se.y * e1 * inv;
    wprev.z = se.z * e2 * inv;
    wprev.w = se.w * e3 * inv;

    x = xn; h = hn; l = ln;
  }
  ((float4*)(out + (size_t)b * 1024))[tid] = lacc;
}

extern "C" void kernel_launch(void* const* d_in, const int* in_sizes, int n_in,
                              void* d_out, int out_size, void* d_ws, size_t ws_size,
                              hipStream_t stream) {
  const float* pred = (const float*)d_in[0];
  const float* tru  = (const float*)d_in[1];
  const float* W    = (const float*)d_in[2];
  const float* bias = (const float*)d_in[3];
  float* out = (float*)d_out;

  char* ws = (char*)d_ws;
  _Float16* se_hi  = (_Float16*)(ws);                    // 128 MB
  _Float16* se_lo  = (_Float16*)(ws + 134217728ull);     // 128 MB
  float*    logits = (float*)   (ws + 268435456ull);     // 256 MB
  _Float16* W_hi   = (_Float16*)(ws + 536870912ull);     // 2 MB
  _Float16* W_lo   = (_Float16*)(ws + 538968064ull);     // 2 MB

  se_split_k<<<2048, 256, 0, stream>>>(pred, tru, se_hi, se_lo);
  w_split_k<<<1024, 256, 0, stream>>>(W, W_hi, W_lo);
  gemm_logits_k<<<4096, 256, 0, stream>>>(se_hi, se_lo, W_hi, W_lo, bias, logits);
  softmax_loss_k<<<1024, 256, 0, stream>>>(logits, se_hi, se_lo, out);
}

// Round 7
// 633.323 us; speedup vs baseline: 1.0809x; 1.0781x over previous
//
#include <hip/hip_runtime.h>
#include <hip/hip_fp16.h>

typedef _Float16 f16x4 __attribute__((ext_vector_type(4)));
typedef _Float16 f16x8 __attribute__((ext_vector_type(8)));
typedef float    f32x4 __attribute__((ext_vector_type(4)));

#define TBD 67108864ull   // T*B*D
#define BD  1048576ull    // B*D

#define ASM_VMCNT(N) asm volatile("s_waitcnt vmcnt(" #N ")" ::: "memory")
#define ASM_LGKM(N)  asm volatile("s_waitcnt lgkmcnt(" #N ")" ::: "memory")
#define BARRIER()    __builtin_amdgcn_s_barrier()
#define SCHED0()     __builtin_amdgcn_sched_barrier(0)
#define MFMA(a,b,c)  __builtin_amdgcn_mfma_f32_16x16x32_f16((a),(b),(c),0,0,0)

// ---------------- Kernel 1: se = (pred-true)^2, split into fp16 hi/lo ----------------
__global__ __launch_bounds__(256) void se_split_k(const float* __restrict__ pred,
                                                  const float* __restrict__ tru,
                                                  _Float16* __restrict__ hi,
                                                  _Float16* __restrict__ lo) {
  size_t stride = (size_t)gridDim.x * 1024;
  for (size_t i = ((size_t)blockIdx.x * 256 + threadIdx.x) * 4; i < TBD; i += stride) {
    float4 p = *(const float4*)(pred + i);
    float4 t = *(const float4*)(tru + i);
    float s0 = (p.x - t.x) * (p.x - t.x);
    float s1 = (p.y - t.y) * (p.y - t.y);
    float s2 = (p.z - t.z) * (p.z - t.z);
    float s3 = (p.w - t.w) * (p.w - t.w);
    f16x4 h, l;
    h[0] = (_Float16)s0; l[0] = (_Float16)(s0 - (float)h[0]);
    h[1] = (_Float16)s1; l[1] = (_Float16)(s1 - (float)h[1]);
    h[2] = (_Float16)s2; l[2] = (_Float16)(s2 - (float)h[2]);
    h[3] = (_Float16)s3; l[3] = (_Float16)(s3 - (float)h[3]);
    *(f16x4*)(hi + i) = h;
    *(f16x4*)(lo + i) = l;
  }
}

// ---------------- Kernel 2: split W into fp16 hi/lo ----------------
__global__ __launch_bounds__(256) void w_split_k(const float* __restrict__ W,
                                                 _Float16* __restrict__ hi,
                                                 _Float16* __restrict__ lo) {
  size_t i = ((size_t)blockIdx.x * 256 + threadIdx.x) * 4;  // covers 1048576 exactly
  float4 x = *(const float4*)(W + i);
  f16x4 h, l;
  h[0] = (_Float16)x.x; l[0] = (_Float16)(x.x - (float)h[0]);
  h[1] = (_Float16)x.y; l[1] = (_Float16)(x.y - (float)h[1]);
  h[2] = (_Float16)x.z; l[2] = (_Float16)(x.z - (float)h[2]);
  h[3] = (_Float16)x.w; l[3] = (_Float16)(x.w - (float)h[3]);
  *(f16x4*)(hi + i) = h;
  *(f16x4*)(lo + i) = l;
}

// ---------------- Kernel 3: logits = SE @ W^T + b (split-fp16 3-pass, m201 8-phase) ----
// M=65536, N=1024, K=1024. Tile 256x256, BK=32 (fp32, hi+lo = 128B/row), 8 waves (2Mx4N),
// per-wave 128x64. LDS: buf0/buf1 = 64KB each, one K-tile per buffer (A 32KB + B 32KB).
// Iteration = 2 K-tiles: kt0=2i (buf0), kt1=2i+1 (buf1). 8 phases; per phase:
// {ds_reads for this quadrant; stage region; barrier; lgkm(0); sched0; setprio(1);
//  24 MFMA; setprio(0); [p3/p7: vmcnt(8)]; barrier}.
// Staging: p2: A(T+2)->buf0, p3: B(T+2)->buf0, p6: A(T+3)->buf1, p7: B(T+3)->buf1
// (each 4 gloads/thread). vmcnt(8) at p3/p7 leaves the newest 8 loads in flight ->
// every staged region lands with ~5-phase lead; never drained to 0 in the loop.
// Row = 8 x 16B slots: hi k0..31 slots 0-3, lo slots 4-7; physical slot = logical ^ (row&7)
// (verified 0 bank conflicts, rounds 2-4; staging source inverse-swizzled).

#define GL4_A(dstb, kof)                                                          \
  _Pragma("unroll")                                                               \
  for (int q = 0; q < 4; ++q)                                                     \
    __builtin_amdgcn_global_load_lds(                                             \
        (const __attribute__((address_space(1))) void*)(aSrc[q] + (kof)),         \
        (__attribute__((address_space(3))) void*)((dstb) + q * 8192 + tid * 16),  \
        16, 0, 0);

#define GL4_B(dstb, kof)                                                          \
  _Pragma("unroll")                                                               \
  for (int q = 0; q < 4; ++q)                                                     \
    __builtin_amdgcn_global_load_lds(                                             \
        (const __attribute__((address_space(1))) void*)(bSrc[q] + (kof)),         \
        (__attribute__((address_space(3))) void*)((dstb) + 32768 + q * 8192 + tid * 16), \
        16, 0, 0);

// 24 MFMAs: one quadrant (4 fi x 2 fj x 3 passes), pass-major (8 indep accs/pass).
#define MQ(f0, j0, A0H, A0L, A1H, A1L, A2H, A2L, A3H, A3L, B0H, B0L, B1H, B1L)  \
  __builtin_amdgcn_s_setprio(1);                                                \
  acc[(f0)+0][(j0)+0] = MFMA(A0H, B0H, acc[(f0)+0][(j0)+0]);                    \
  acc[(f0)+1][(j0)+0] = MFMA(A1H, B0H, acc[(f0)+1][(j0)+0]);                    \
  acc[(f0)+2][(j0)+0] = MFMA(A2H, B0H, acc[(f0)+2][(j0)+0]);                    \
  acc[(f0)+3][(j0)+0] = MFMA(A3H, B0H, acc[(f0)+3][(j0)+0]);                    \
  acc[(f0)+0][(j0)+1] = MFMA(A0H, B1H, acc[(f0)+0][(j0)+1]);                    \
  acc[(f0)+1][(j0)+1] = MFMA(A1H, B1H, acc[(f0)+1][(j0)+1]);                    \
  acc[(f0)+2][(j0)+1] = MFMA(A2H, B1H, acc[(f0)+2][(j0)+1]);                    \
  acc[(f0)+3][(j0)+1] = MFMA(A3H, B1H, acc[(f0)+3][(j0)+1]);                    \
  acc[(f0)+0][(j0)+0] = MFMA(A0L, B0H, acc[(f0)+0][(j0)+0]);                    \
  acc[(f0)+1][(j0)+0] = MFMA(A1L, B0H, acc[(f0)+1][(j0)+0]);                    \
  acc[(f0)+2][(j0)+0] = MFMA(A2L, B0H, acc[(f0)+2][(j0)+0]);                    \
  acc[(f0)+3][(j0)+0] = MFMA(A3L, B0H, acc[(f0)+3][(j0)+0]);                    \
  acc[(f0)+0][(j0)+1] = MFMA(A0L, B1H, acc[(f0)+0][(j0)+1]);                    \
  acc[(f0)+1][(j0)+1] = MFMA(A1L, B1H, acc[(f0)+1][(j0)+1]);                    \
  acc[(f0)+2][(j0)+1] = MFMA(A2L, B1H, acc[(f0)+2][(j0)+1]);                    \
  acc[(f0)+3][(j0)+1] = MFMA(A3L, B1H, acc[(f0)+3][(j0)+1]);                    \
  acc[(f0)+0][(j0)+0] = MFMA(A0H, B0L, acc[(f0)+0][(j0)+0]);                    \
  acc[(f0)+1][(j0)+0] = MFMA(A1H, B0L, acc[(f0)+1][(j0)+0]);                    \
  acc[(f0)+2][(j0)+0] = MFMA(A2H, B0L, acc[(f0)+2][(j0)+0]);                    \
  acc[(f0)+3][(j0)+0] = MFMA(A3H, B0L, acc[(f0)+3][(j0)+0]);                    \
  acc[(f0)+0][(j0)+1] = MFMA(A0H, B1L, acc[(f0)+0][(j0)+1]);                    \
  acc[(f0)+1][(j0)+1] = MFMA(A1H, B1L, acc[(f0)+1][(j0)+1]);                    \
  acc[(f0)+2][(j0)+1] = MFMA(A2H, B1L, acc[(f0)+2][(j0)+1]);                    \
  acc[(f0)+3][(j0)+1] = MFMA(A3H, B1L, acc[(f0)+3][(j0)+1]);                    \
  __builtin_amdgcn_s_setprio(0);

#define LD(buf, off) (*(const f16x8*)((buf) + (off)))

__global__ __launch_bounds__(512, 2) void gemm_logits_k(
    const _Float16* __restrict__ Ah, const _Float16* __restrict__ Al,
    const _Float16* __restrict__ Wh, const _Float16* __restrict__ Wl,
    const float* __restrict__ bias, float* __restrict__ C) {
  __shared__ uint4 lds4[8192];  // 128 KiB
  char* lds = (char*)lds4;
  char* buf0 = lds;
  char* buf1 = lds + 65536;
  const int tid = threadIdx.x;
  const int lane = tid & 63;
  const int wid = tid >> 6;          // 0..7
  const int wr = wid >> 2;           // 0..1 (M)
  const int wc = wid & 3;            // 0..3 (N)

  // XCD-aware bijective swizzle: 1024 blocks, 8 XCDs, 128 per XCD.
  const int bid = blockIdx.x;
  const int wgid = (bid & 7) * 128 + (bid >> 3);
  const int bm = wgid >> 2, bn = wgid & 3;   // 256 M-tiles x 4 N-tiles
  const int row0 = bm * 256, col0 = bn * 256;

  // Staging source addresses (inverse-swizzled), 4 A + 4 B chunks of 16B per thread.
  const _Float16* aSrc[4];
  const _Float16* bSrc[4];
#pragma unroll
  for (int q = 0; q < 4; ++q) {
    int p = q * 8192 + tid * 16;      // byte offset in 32KB region
    int r = p >> 7;                   // row 0..255
    int s = (p >> 4) & 7;             // physical slot
    int sig = s ^ (r & 7);            // logical slot (involution)
    size_t koff = (size_t)(sig & 3) * 8;
    aSrc[q] = (sig < 4 ? Ah : Al) + ((size_t)(row0 + r) * 1024 + koff);
    bSrc[q] = (sig < 4 ? Wh : Wl) + ((size_t)(col0 + r) * 1024 + koff);
  }

  // Fragment read offsets (relative to buffer base); verified conflict-free.
  const int u = lane >> 4;           // 0..3 -> k = 8u
  const int sw = lane & 7;
  const int aRow = wr * 128 + (lane & 15);
  const int bRow = wc * 64 + (lane & 15);
  const int aoffH = aRow * 128 + ((u)     ^ sw) * 16;
  const int aoffL = aRow * 128 + ((u + 4) ^ sw) * 16;
  const int boffH = 32768 + bRow * 128 + ((u)     ^ sw) * 16;
  const int boffL = 32768 + bRow * 128 + ((u + 4) ^ sw) * 16;

  f32x4 acc[8][4] = {};

  // Prologue: tile 0 -> buf0, tile 1 -> buf1; vmcnt(8) leaves tile 1's loads in flight.
  GL4_A(buf0, 0)
  GL4_B(buf0, 0)
  GL4_A(buf1, 32)
  GL4_B(buf1, 32)
  ASM_VMCNT(8);
  BARRIER();

#pragma unroll 1
  for (int i = 0; i < 16; ++i) {
    const size_t kof2 = (size_t)((2 * i + 2) & 31) * 32;  // tile for buf0 (tail wraps, dead)
    const size_t kof3 = (size_t)((2 * i + 3) & 31) * 32;  // tile for buf1

    f16x8 a0h, a0l, a1h, a1l, a2h, a2l, a3h, a3l;
    f16x8 a4h, a4l, a5h, a5l, a6h, a6l, a7h, a7l;
    f16x8 b0h, b0l, b1h, b1l, b2h, b2l, b3h, b3l;

    // ---------- p0: reads A0-3(kt0)+B01(kt0); MFMA q0 ----------
    a0h = LD(buf0, aoffH + 0 * 2048); a0l = LD(buf0, aoffL + 0 * 2048);
    a1h = LD(buf0, aoffH + 1 * 2048); a1l = LD(buf0, aoffL + 1 * 2048);
    a2h = LD(buf0, aoffH + 2 * 2048); a2l = LD(buf0, aoffL + 2 * 2048);
    a3h = LD(buf0, aoffH + 3 * 2048); a3l = LD(buf0, aoffL + 3 * 2048);
    b0h = LD(buf0, boffH + 0 * 2048); b0l = LD(buf0, boffL + 0 * 2048);
    b1h = LD(buf0, boffH + 1 * 2048); b1l = LD(buf0, boffL + 1 * 2048);
    BARRIER(); ASM_LGKM(0); SCHED0();
    MQ(0, 0, a0h, a0l, a1h, a1l, a2h, a2l, a3h, a3l, b0h, b0l, b1h, b1l)
    BARRIER();

    // ---------- p1: reads A4-7(kt0); MFMA q1 ----------
    a4h = LD(buf0, aoffH + 4 * 2048); a4l = LD(buf0, aoffL + 4 * 2048);
    a5h = LD(buf0, aoffH + 5 * 2048); a5l = LD(buf0, aoffL + 5 * 2048);
    a6h = LD(buf0, aoffH + 6 * 2048); a6l = LD(buf0, aoffL + 6 * 2048);
    a7h = LD(buf0, aoffH + 7 * 2048); a7l = LD(buf0, aoffL + 7 * 2048);
    BARRIER(); ASM_LGKM(0); SCHED0();
    MQ(4, 0, a4h, a4l, a5h, a5l, a6h, a6l, a7h, a7l, b0h, b0l, b1h, b1l)
    BARRIER();

    // ---------- p2: reads B23(kt0); stage A(T+2)->buf0; MFMA q2 ----------
    b2h = LD(buf0, boffH + 2 * 2048); b2l = LD(buf0, boffL + 2 * 2048);
    b3h = LD(buf0, boffH + 3 * 2048); b3l = LD(buf0, boffL + 3 * 2048);
    GL4_A(buf0, kof2)
    BARRIER(); ASM_LGKM(0); SCHED0();
    MQ(4, 2, a4h, a4l, a5h, a5l, a6h, a6l, a7h, a7l, b2h, b2l, b3h, b3l)
    BARRIER();

    // ---------- p3: stage B(T+2)->buf0; MFMA q3; vmcnt(8) ----------
    GL4_B(buf0, kof2)
    BARRIER(); SCHED0();
    MQ(0, 2, a0h, a0l, a1h, a1l, a2h, a2l, a3h, a3l, b2h, b2l, b3h, b3l)
    ASM_VMCNT(8);
    BARRIER();

    // ---------- p4: reads A0-3(kt1)+B01(kt1); MFMA q0' ----------
    a0h = LD(buf1, aoffH + 0 * 2048); a0l = LD(buf1, aoffL + 0 * 2048);
    a1h = LD(buf1, aoffH + 1 * 2048); a1l = LD(buf1, aoffL + 1 * 2048);
    a2h = LD(buf1, aoffH + 2 * 2048); a2l = LD(buf1, aoffL + 2 * 2048);
    a3h = LD(buf1, aoffH + 3 * 2048); a3l = LD(buf1, aoffL + 3 * 2048);
    b0h = LD(buf1, boffH + 0 * 2048); b0l = LD(buf1, boffL + 0 * 2048);
    b1h = LD(buf1, boffH + 1 * 2048); b1l = LD(buf1, boffL + 1 * 2048);
    BARRIER(); ASM_LGKM(0); SCHED0();
    MQ(0, 0, a0h, a0l, a1h, a1l, a2h, a2l, a3h, a3l, b0h, b0l, b1h, b1l)
    BARRIER();

    // ---------- p5: reads A4-7(kt1); MFMA q1' ----------
    a4h = LD(buf1, aoffH + 4 * 2048); a4l = LD(buf1, aoffL + 4 * 2048);
    a5h = LD(buf1, aoffH + 5 * 2048); a5l = LD(buf1, aoffL + 5 * 2048);
    a6h = LD(buf1, aoffH + 6 * 2048); a6l = LD(buf1, aoffL + 6 * 2048);
    a7h = LD(buf1, aoffH + 7 * 2048); a7l = LD(buf1, aoffL + 7 * 2048);
    BARRIER(); ASM_LGKM(0); SCHED0();
    MQ(4, 0, a4h, a4l, a5h, a5l, a6h, a6l, a7h, a7l, b0h, b0l, b1h, b1l)
    BARRIER();

    // ---------- p6: reads B23(kt1); stage A(T+3)->buf1; MFMA q2' ----------
    b2h = LD(buf1, boffH + 2 * 2048); b2l = LD(buf1, boffL + 2 * 2048);
    b3h = LD(buf1, boffH + 3 * 2048); b3l = LD(buf1, boffL + 3 * 2048);
    GL4_A(buf1, kof3)
    BARRIER(); ASM_LGKM(0); SCHED0();
    MQ(4, 2, a4h, a4l, a5h, a5l, a6h, a6l, a7h, a7l, b2h, b2l, b3h, b3l)
    BARRIER();

    // ---------- p7: stage B(T+3)->buf1; MFMA q3'; vmcnt(8) ----------
    GL4_B(buf1, kof3)
    BARRIER(); SCHED0();
    MQ(0, 2, a0h, a0l, a1h, a1l, a2h, a2l, a3h, a3l, b2h, b2l, b3h, b3l)
    ASM_VMCNT(8);
    BARRIER();
  }
  ASM_VMCNT(0);    // drain tail dummy loads

  // Epilogue: C[i,j] = acc + bias[j].  C/D: col=lane&15, row=(lane>>4)*4+q.
#pragma unroll
  for (int fj = 0; fj < 4; ++fj) {
    int c = col0 + wc * 64 + fj * 16 + (lane & 15);
    float bj = bias[c];
#pragma unroll
    for (int fi = 0; fi < 8; ++fi) {
      int r = row0 + wr * 128 + fi * 16 + u * 4;
#pragma unroll
      for (int q = 0; q < 4; ++q)
        C[(size_t)(r + q) * 1024 + c] = acc[fi][fj][q] + bj;
    }
  }
}

// ---------------- Kernel 4: fused softmax + gating + loss accumulation ----------------
__global__ __launch_bounds__(256) void softmax_loss_k(const float* __restrict__ logits,
                                                      const _Float16* __restrict__ hi,
                                                      const _Float16* __restrict__ lo,
                                                      float* __restrict__ out) {
  const int b = blockIdx.x;            // 0..1023
  const int tid = threadIdx.x, lane = tid & 63, wid = tid >> 6;
  __shared__ float red[8];
  float4 wprev = make_float4(1.f, 1.f, 1.f, 1.f);
  float4 lacc  = make_float4(0.f, 0.f, 0.f, 0.f);

  size_t base = (size_t)b * 1024;      // row (t=0, b)
  float4 x = ((const float4*)(logits + base))[tid];
  f16x4  h = ((const f16x4*)(hi + base))[tid];
  f16x4  l = ((const f16x4*)(lo + base))[tid];

#pragma unroll 1
  for (int t = 0; t < 64; ++t) {
    float4 se;
    se.x = (float)h[0] + (float)l[0];
    se.y = (float)h[1] + (float)l[1];
    se.z = (float)h[2] + (float)l[2];
    se.w = (float)h[3] + (float)l[3];
    lacc.x += wprev.x * se.x;
    lacc.y += wprev.y * se.y;
    lacc.z += wprev.z * se.z;
    lacc.w += wprev.w * se.w;

    int tn = (t + 1 < 64) ? t + 1 : t;
    size_t nbase = ((size_t)tn * 1024 + (size_t)b) * 1024;
    float4 xn = ((const float4*)(logits + nbase))[tid];
    f16x4  hn = ((const f16x4*)(hi + nbase))[tid];
    f16x4  ln = ((const f16x4*)(lo + nbase))[tid];

    float m = fmaxf(fmaxf(x.x, x.y), fmaxf(x.z, x.w));
#pragma unroll
    for (int o = 32; o >= 1; o >>= 1) m = fmaxf(m, __shfl_xor(m, o, 64));
    if (lane == 0) red[wid] = m;
    __syncthreads();
    m = fmaxf(fmaxf(red[0], red[1]), fmaxf(red[2], red[3]));
    float e0 = __expf(x.x - m), e1 = __expf(x.y - m), e2 = __expf(x.z - m), e3 = __expf(x.w - m);
    float s = (e0 + e1) + (e2 + e3);
#pragma unroll
    for (int o = 32; o >= 1; o >>= 1) s += __shfl_xor(s, o, 64);
    if (lane == 0) red[4 + wid] = s;
    __syncthreads();
    s = (red[4] + red[5]) + (red[6] + red[7]);
    float inv = 1.0f / s;

    wprev.x = se.x * e0 * inv;
    wprev.y = se.y * e1 * inv;
    wprev.z = se.z * e2 * inv;
    wprev.w = se.w * e3 * inv;

    x = xn; h = hn; l = ln;
  }
  ((float4*)(out + (size_t)b * 1024))[tid] = lacc;
}

extern "C" void kernel_launch(void* const* d_in, const int* in_sizes, int n_in,
                              void* d_out, int out_size, void* d_ws, size_t ws_size,
                              hipStream_t stream) {
  const float* pred = (const float*)d_in[0];
  const float* tru  = (const float*)d_in[1];
  const float* W    = (const float*)d_in[2];
  const float* bias = (const float*)d_in[3];
  float* out = (float*)d_out;

  char* ws = (char*)d_ws;
  _Float16* se_hi  = (_Float16*)(ws);                    // 128 MB
  _Float16* se_lo  = (_Float16*)(ws + 134217728ull);     // 128 MB
  float*    logits = (float*)   (ws + 268435456ull);     // 256 MB
  _Float16* W_hi   = (_Float16*)(ws + 536870912ull);     // 2 MB
  _Float16* W_lo   = (_Float16*)(ws + 538968064ull);     // 2 MB

  se_split_k<<<2048, 256, 0, stream>>>(pred, tru, se_hi, se_lo);
  w_split_k<<<1024, 256, 0, stream>>>(W, W_hi, W_lo);
  gemm_logits_k<<<1024, 512, 0, stream>>>(se_hi, se_lo, W_hi, W_lo, bias, logits);
  softmax_loss_k<<<1024, 256, 0, stream>>>(logits, se_hi, se_lo, out);
}

// Round 8
// 529.810 us; speedup vs baseline: 1.2921x; 1.1954x over previous
//
#include <hip/hip_runtime.h>
#include <hip/hip_fp16.h>

typedef _Float16 f16x4 __attribute__((ext_vector_type(4)));
typedef _Float16 f16x8 __attribute__((ext_vector_type(8)));
typedef float    f32x4 __attribute__((ext_vector_type(4)));

#define TBD 67108864ull   // T*B*D
#define BD  1048576ull    // B*D

#define ASM_VMCNT(N) asm volatile("s_waitcnt vmcnt(" #N ")" ::: "memory")
#define ASM_LGKM(N)  asm volatile("s_waitcnt lgkmcnt(" #N ")" ::: "memory")
#define BARRIER()    __builtin_amdgcn_s_barrier()
#define MFMA(a,b,c)  __builtin_amdgcn_mfma_f32_16x16x32_f16((a),(b),(c),0,0,0)

// ---------------- Kernel 1: se = (pred-true)^2, split into fp16 hi/lo ----------------
__global__ __launch_bounds__(256) void se_split_k(const float* __restrict__ pred,
                                                  const float* __restrict__ tru,
                                                  _Float16* __restrict__ hi,
                                                  _Float16* __restrict__ lo) {
  size_t stride = (size_t)gridDim.x * 1024;
  for (size_t i = ((size_t)blockIdx.x * 256 + threadIdx.x) * 4; i < TBD; i += stride) {
    float4 p = *(const float4*)(pred + i);
    float4 t = *(const float4*)(tru + i);
    float s0 = (p.x - t.x) * (p.x - t.x);
    float s1 = (p.y - t.y) * (p.y - t.y);
    float s2 = (p.z - t.z) * (p.z - t.z);
    float s3 = (p.w - t.w) * (p.w - t.w);
    f16x4 h, l;
    h[0] = (_Float16)s0; l[0] = (_Float16)(s0 - (float)h[0]);
    h[1] = (_Float16)s1; l[1] = (_Float16)(s1 - (float)h[1]);
    h[2] = (_Float16)s2; l[2] = (_Float16)(s2 - (float)h[2]);
    h[3] = (_Float16)s3; l[3] = (_Float16)(s3 - (float)h[3]);
    *(f16x4*)(hi + i) = h;
    *(f16x4*)(lo + i) = l;
  }
}

// ---------------- Kernel 2: W -> fp16 hi only (2-pass GEMM never uses W_lo) ----------
__global__ __launch_bounds__(256) void w_split_k(const float* __restrict__ W,
                                                 _Float16* __restrict__ hi) {
  size_t i = ((size_t)blockIdx.x * 256 + threadIdx.x) * 4;  // covers 1048576 exactly
  float4 x = *(const float4*)(W + i);
  f16x4 h;
  h[0] = (_Float16)x.x; h[1] = (_Float16)x.y; h[2] = (_Float16)x.z; h[3] = (_Float16)x.w;
  *(f16x4*)(hi + i) = h;
}

// ---------------- Kernel 3: logits = SE @ Wh^T + b  (split-fp16 2-pass MFMA) ----------
// M=65536, N=1024, K=1024. Tile 256x256, BK=32, 8 waves (4M x 2N), per-wave 64x128.
// 2-pass: logits = (Ah+Al)·Bh  (A=se hi/lo; B=Wh only -> B LDS region halved).
// LDS: 2 buffers x 48KB = 96KB. Buffer = A[256 rows][128B] + B[256 rows][64B hi].
//   A row = 8x16B slots (hi 0-3, lo 4-7), phys = logical ^ (row&7)        [r2-verified]
//   B row = 4x16B slots (hi k-chunks),  phys = logical ^ ((row^(row>>2))&3)
//   (8-lane-beat bank model: both layouts give 8 distinct 16B chunks per beat -> 0 conflicts)
// K-loop = round-3 proven shape: vmcnt(6); barrier; 16 ds_reads; lgkm-fenced
// pass-major MFMA clusters; all-reads barrier; stage 6 loads (4A+2B) for t+2.

#define GL4_A(dstb, kof)                                                          \
  _Pragma("unroll")                                                               \
  for (int q = 0; q < 4; ++q)                                                     \
    __builtin_amdgcn_global_load_lds(                                             \
        (const __attribute__((address_space(1))) void*)(aSrc[q] + (kof)),         \
        (__attribute__((address_space(3))) void*)((dstb) + q * 8192 + tid * 16),  \
        16, 0, 0);

#define GL2_B(dstb, kof)                                                          \
  _Pragma("unroll")                                                               \
  for (int q = 0; q < 2; ++q)                                                     \
    __builtin_amdgcn_global_load_lds(                                             \
        (const __attribute__((address_space(1))) void*)(bSrc[q] + (kof)),         \
        (__attribute__((address_space(3))) void*)((dstb) + 32768 + q * 8192 + tid * 16), \
        16, 0, 0);

// 16 MFMAs: fj-pair cluster, pass-major (H then L), 8 independent accs per pass.
#define MCL(j0, B0, B1)                                  \
  __builtin_amdgcn_s_setprio(1);                         \
  acc[0][(j0)]   = MFMA(a0h, B0, acc[0][(j0)]);          \
  acc[1][(j0)]   = MFMA(a1h, B0, acc[1][(j0)]);          \
  acc[2][(j0)]   = MFMA(a2h, B0, acc[2][(j0)]);          \
  acc[3][(j0)]   = MFMA(a3h, B0, acc[3][(j0)]);          \
  acc[0][(j0)+1] = MFMA(a0h, B1, acc[0][(j0)+1]);        \
  acc[1][(j0)+1] = MFMA(a1h, B1, acc[1][(j0)+1]);        \
  acc[2][(j0)+1] = MFMA(a2h, B1, acc[2][(j0)+1]);        \
  acc[3][(j0)+1] = MFMA(a3h, B1, acc[3][(j0)+1]);        \
  acc[0][(j0)]   = MFMA(a0l, B0, acc[0][(j0)]);          \
  acc[1][(j0)]   = MFMA(a1l, B0, acc[1][(j0)]);          \
  acc[2][(j0)]   = MFMA(a2l, B0, acc[2][(j0)]);          \
  acc[3][(j0)]   = MFMA(a3l, B0, acc[3][(j0)]);          \
  acc[0][(j0)+1] = MFMA(a0l, B1, acc[0][(j0)+1]);        \
  acc[1][(j0)+1] = MFMA(a1l, B1, acc[1][(j0)+1]);        \
  acc[2][(j0)+1] = MFMA(a2l, B1, acc[2][(j0)+1]);        \
  acc[3][(j0)+1] = MFMA(a3l, B1, acc[3][(j0)+1]);        \
  __builtin_amdgcn_s_setprio(0);

#define LD(buf, off) (*(const f16x8*)((buf) + (off)))

__global__ __launch_bounds__(512, 2) void gemm_logits_k(
    const _Float16* __restrict__ Ah, const _Float16* __restrict__ Al,
    const _Float16* __restrict__ Wh,
    const float* __restrict__ bias, float* __restrict__ C) {
  __shared__ uint4 lds4[6144];  // 96 KiB
  char* lds = (char*)lds4;
  const int tid = threadIdx.x;
  const int lane = tid & 63;
  const int wid = tid >> 6;          // 0..7
  const int wm = wid >> 1;           // 0..3 (M)
  const int wn = wid & 1;            // 0..1 (N)

  // XCD-aware bijective swizzle: 1024 blocks, 8 XCDs, 128 per XCD.
  const int bid = blockIdx.x;
  const int wgid = (bid & 7) * 128 + (bid >> 3);
  const int bm = wgid >> 2, bn = wgid & 3;   // 256 M-tiles x 4 N-tiles
  const int row0 = bm * 256, col0 = bn * 256;

  // Staging sources (inverse-swizzled). A: 4 chunks/thread; B: 2 chunks/thread.
  const _Float16* aSrc[4];
  const _Float16* bSrc[2];
#pragma unroll
  for (int q = 0; q < 4; ++q) {
    int p = q * 8192 + tid * 16;      // byte offset in A region (32KB)
    int r = p >> 7;                   // row 0..255 (128B rows)
    int s = (p >> 4) & 7;             // physical slot
    int sig = s ^ (r & 7);            // logical slot (involution)
    size_t koff = (size_t)(sig & 3) * 8;
    aSrc[q] = (sig < 4 ? Ah : Al) + ((size_t)(row0 + r) * 1024 + koff);
  }
#pragma unroll
  for (int q = 0; q < 2; ++q) {
    int p = q * 8192 + tid * 16;      // byte offset in B region (16KB)
    int r = p >> 6;                   // row 0..255 (64B rows)
    int s = (p >> 4) & 3;             // physical slot
    int sig = s ^ ((r ^ (r >> 2)) & 3);  // logical slot (involution)
    bSrc[q] = Wh + ((size_t)(col0 + r) * 1024 + (size_t)sig * 8);
  }

  // Fragment read offsets.
  const int u = lane >> 4;           // 0..3 -> k-chunk
  const int sw = lane & 7;           // = row&7 for A rows (base mult of 16)
  const int bsw = (lane ^ (lane >> 2)) & 3;  // = (row^(row>>2))&3 for B rows
  const int aRow = wm * 64 + (lane & 15);
  const int bRow = wn * 128 + (lane & 15);
  const int aoffH = aRow * 128 + ((u)     ^ sw) * 16;
  const int aoffL = aRow * 128 + ((u + 4) ^ sw) * 16;
  const int boffH = 32768 + bRow * 64 + ((u ^ bsw) * 16);

  f32x4 acc[4][8] = {};

  // Prologue: tile 0 -> buf0, tile 1 -> buf1; vmcnt(6) -> tile 0 resident.
  char* buf0 = lds;
  char* buf1 = lds + 49152;
  GL4_A(buf0, 0)
  GL2_B(buf0, 0)
  GL4_A(buf1, 32)
  GL2_B(buf1, 32)
  ASM_VMCNT(6);
  BARRIER();

#pragma unroll 1
  for (int t = 0; t < 32; ++t) {
    char* ldsb = lds + (t & 1) * 49152;
    const int tt = (t + 2 < 32) ? t + 2 : 31;   // dummy tail reload keeps vmcnt cadence
    const size_t kof = (size_t)tt * 32;

    // 16 ds_reads: A first (8), then B (8)
    f16x8 a0h = LD(ldsb, aoffH + 0 * 2048);
    f16x8 a0l = LD(ldsb, aoffL + 0 * 2048);
    f16x8 a1h = LD(ldsb, aoffH + 1 * 2048);
    f16x8 a1l = LD(ldsb, aoffL + 1 * 2048);
    f16x8 a2h = LD(ldsb, aoffH + 2 * 2048);
    f16x8 a2l = LD(ldsb, aoffL + 2 * 2048);
    f16x8 a3h = LD(ldsb, aoffH + 3 * 2048);
    f16x8 a3l = LD(ldsb, aoffL + 3 * 2048);
    f16x8 b0 = LD(ldsb, boffH + 0 * 1024);
    f16x8 b1 = LD(ldsb, boffH + 1 * 1024);
    f16x8 b2 = LD(ldsb, boffH + 2 * 1024);
    f16x8 b3 = LD(ldsb, boffH + 3 * 1024);
    f16x8 b4 = LD(ldsb, boffH + 4 * 1024);
    f16x8 b5 = LD(ldsb, boffH + 5 * 1024);
    f16x8 b6 = LD(ldsb, boffH + 6 * 1024);
    f16x8 b7 = LD(ldsb, boffH + 7 * 1024);
    ASM_LGKM(6);               // A(8) + B0,B1 resident
    MCL(0, b0, b1)
    ASM_LGKM(4);               // B2,B3
    MCL(2, b2, b3)
    ASM_LGKM(2);               // B4,B5
    MCL(4, b4, b5)
    ASM_LGKM(0);               // all reads of ldsb done
    BARRIER();                 // every wave done reading -> safe to overwrite
    GL4_A(ldsb, kof)           // stage tile t+2 (6 loads)
    GL2_B(ldsb, kof)
    MCL(6, b6, b7)
    ASM_VMCNT(6);              // tile t+1's 6 loads landed (t+2's 6 in flight)
    BARRIER();
  }
  ASM_VMCNT(0);    // drain tail dummy loads

  // Epilogue: C[i,j] = acc + bias[j].  C/D: col=lane&15, row=(lane>>4)*4+q.
#pragma unroll
  for (int fj = 0; fj < 8; ++fj) {
    int c = col0 + wn * 128 + fj * 16 + (lane & 15);
    float bj = bias[c];
#pragma unroll
    for (int fi = 0; fi < 4; ++fi) {
      int r = row0 + wm * 64 + fi * 16 + u * 4;
#pragma unroll
      for (int q = 0; q < 4; ++q)
        C[(size_t)(r + q) * 1024 + c] = acc[fi][fj][q] + bj;
    }
  }
}

// ---------------- Kernel 4: fused softmax + gating + loss accumulation ----------------
__global__ __launch_bounds__(256) void softmax_loss_k(const float* __restrict__ logits,
                                                      const _Float16* __restrict__ hi,
                                                      const _Float16* __restrict__ lo,
                                                      float* __restrict__ out) {
  const int b = blockIdx.x;            // 0..1023
  const int tid = threadIdx.x, lane = tid & 63, wid = tid >> 6;
  __shared__ float red[8];
  float4 wprev = make_float4(1.f, 1.f, 1.f, 1.f);
  float4 lacc  = make_float4(0.f, 0.f, 0.f, 0.f);

  size_t base = (size_t)b * 1024;      // row (t=0, b)
  float4 x = ((const float4*)(logits + base))[tid];
  f16x4  h = ((const f16x4*)(hi + base))[tid];
  f16x4  l = ((const f16x4*)(lo + base))[tid];

#pragma unroll 1
  for (int t = 0; t < 64; ++t) {
    float4 se;
    se.x = (float)h[0] + (float)l[0];
    se.y = (float)h[1] + (float)l[1];
    se.z = (float)h[2] + (float)l[2];
    se.w = (float)h[3] + (float)l[3];
    lacc.x += wprev.x * se.x;
    lacc.y += wprev.y * se.y;
    lacc.z += wprev.z * se.z;
    lacc.w += wprev.w * se.w;

    int tn = (t + 1 < 64) ? t + 1 : t;
    size_t nbase = ((size_t)tn * 1024 + (size_t)b) * 1024;
    float4 xn = ((const float4*)(logits + nbase))[tid];
    f16x4  hn = ((const f16x4*)(hi + nbase))[tid];
    f16x4  ln = ((const f16x4*)(lo + nbase))[tid];

    float m = fmaxf(fmaxf(x.x, x.y), fmaxf(x.z, x.w));
#pragma unroll
    for (int o = 32; o >= 1; o >>= 1) m = fmaxf(m, __shfl_xor(m, o, 64));
    if (lane == 0) red[wid] = m;
    __syncthreads();
    m = fmaxf(fmaxf(red[0], red[1]), fmaxf(red[2], red[3]));
    float e0 = __expf(x.x - m), e1 = __expf(x.y - m), e2 = __expf(x.z - m), e3 = __expf(x.w - m);
    float s = (e0 + e1) + (e2 + e3);
#pragma unroll
    for (int o = 32; o >= 1; o >>= 1) s += __shfl_xor(s, o, 64);
    if (lane == 0) red[4 + wid] = s;
    __syncthreads();
    s = (red[4] + red[5]) + (red[6] + red[7]);
    float inv = 1.0f / s;

    wprev.x = se.x * e0 * inv;
    wprev.y = se.y * e1 * inv;
    wprev.z = se.z * e2 * inv;
    wprev.w = se.w * e3 * inv;

    x = xn; h = hn; l = ln;
  }
  ((float4*)(out + (size_t)b * 1024))[tid] = lacc;
}

extern "C" void kernel_launch(void* const* d_in, const int* in_sizes, int n_in,
                              void* d_out, int out_size, void* d_ws, size_t ws_size,
                              hipStream_t stream) {
  const float* pred = (const float*)d_in[0];
  const float* tru  = (const float*)d_in[1];
  const float* W    = (const float*)d_in[2];
  const float* bias = (const float*)d_in[3];
  float* out = (float*)d_out;

  char* ws = (char*)d_ws;
  _Float16* se_hi  = (_Float16*)(ws);                    // 128 MB
  _Float16* se_lo  = (_Float16*)(ws + 134217728ull);     // 128 MB
  float*    logits = (float*)   (ws + 268435456ull);     // 256 MB
  _Float16* W_hi   = (_Float16*)(ws + 536870912ull);     // 2 MB

  se_split_k<<<2048, 256, 0, stream>>>(pred, tru, se_hi, se_lo);
  w_split_k<<<1024, 256, 0, stream>>>(W, W_hi);
  gemm_logits_k<<<1024, 512, 0, stream>>>(se_hi, se_lo, W_hi, bias, logits);
  softmax_loss_k<<<1024, 256, 0, stream>>>(logits, se_hi, se_lo, out);
}

// Round 9
// 375.127 us; speedup vs baseline: 1.8248x; 1.4123x over previous
//
#include <hip/hip_runtime.h>
#include <hip/hip_fp16.h>

typedef _Float16 f16x4 __attribute__((ext_vector_type(4)));
typedef _Float16 f16x8 __attribute__((ext_vector_type(8)));
typedef float    f32x4 __attribute__((ext_vector_type(4)));

#define TBD 67108864ull   // T*B*D
#define BD  1048576ull    // B*D

#define ASM_VMCNT(N) asm volatile("s_waitcnt vmcnt(" #N ")" ::: "memory")
#define ASM_LGKM(N)  asm volatile("s_waitcnt lgkmcnt(" #N ")" ::: "memory")
#define BARRIER()    __builtin_amdgcn_s_barrier()
#define MFMA(a,b,c)  __builtin_amdgcn_mfma_f32_16x16x32_f16((a),(b),(c),0,0,0)

// ---------------- Kernel 1: se = (pred-true)^2 -> fp16 (hi only) ----------------
__global__ __launch_bounds__(256) void se_split_k(const float* __restrict__ pred,
                                                  const float* __restrict__ tru,
                                                  _Float16* __restrict__ hi) {
  size_t stride = (size_t)gridDim.x * 1024;
  for (size_t i = ((size_t)blockIdx.x * 256 + threadIdx.x) * 4; i < TBD; i += stride) {
    float4 p = *(const float4*)(pred + i);
    float4 t = *(const float4*)(tru + i);
    f16x4 h;
    h[0] = (_Float16)((p.x - t.x) * (p.x - t.x));
    h[1] = (_Float16)((p.y - t.y) * (p.y - t.y));
    h[2] = (_Float16)((p.z - t.z) * (p.z - t.z));
    h[3] = (_Float16)((p.w - t.w) * (p.w - t.w));
    *(f16x4*)(hi + i) = h;
  }
}

// ---------------- Kernel 2: W -> fp16 ----------------
__global__ __launch_bounds__(256) void w_split_k(const float* __restrict__ W,
                                                 _Float16* __restrict__ hi) {
  size_t i = ((size_t)blockIdx.x * 256 + threadIdx.x) * 4;  // covers 1048576 exactly
  float4 x = *(const float4*)(W + i);
  f16x4 h;
  h[0] = (_Float16)x.x; h[1] = (_Float16)x.y; h[2] = (_Float16)x.z; h[3] = (_Float16)x.w;
  *(f16x4*)(hi + i) = h;
}

// ---------------- Kernel 3: logits = SE @ Wh^T + b  (single-pass fp16 MFMA) ----------
// M=65536, N=1024, K=1024. Block-tile 128x256, BK=32, 4 waves (2M x 2N),
// wave-tile 64x128 (0.375 ds_reads per MFMA -- LDS throughput is the floor, r8 lesson).
// 2 blocks/CU (48KB LDS, 256 thr): independent barrier domains.
// LDS "super-row" layout (restores the r2-verified zero-conflict 8-slot pattern
// despite 64B of K per row): super-row s = rows {2s, 2s+1}, 128B = 8 x 16B slots;
// logical slot ls = kchunk + 4*(row&1); physical = ls ^ (srow&7)  [involution].
// Buffer = A [64 srows][128B] (8KB) + B [128 srows][128B] (16KB) = 24KB; dbuf 48KB.
// K-loop cadence (r3/r8-proven): 12 ds_reads; lgkm(6/4/2/0)-fenced MFMA clusters;
// all-reads barrier; stage 6 loads for t+2; counted vmcnt(6), never drained in loop.

#define GL2_A(dstb, kof)                                                          \
  _Pragma("unroll")                                                               \
  for (int q = 0; q < 2; ++q)                                                     \
    __builtin_amdgcn_global_load_lds(                                             \
        (const __attribute__((address_space(1))) void*)(aSrc[q] + (kof)),         \
        (__attribute__((address_space(3))) void*)((dstb) + q * 4096 + tid * 16),  \
        16, 0, 0);

#define GL4_B(dstb, kof)                                                          \
  _Pragma("unroll")                                                               \
  for (int q = 0; q < 4; ++q)                                                     \
    __builtin_amdgcn_global_load_lds(                                             \
        (const __attribute__((address_space(1))) void*)(bSrc[q] + (kof)),         \
        (__attribute__((address_space(3))) void*)((dstb) + 8192 + q * 4096 + tid * 16), \
        16, 0, 0);

// 8 MFMAs per cluster: 8 independent accumulators (4 fi x 2 fj).
#define MCL(j0, B0, B1)                                  \
  __builtin_amdgcn_s_setprio(1);                         \
  acc[0][(j0)]   = MFMA(a0, B0, acc[0][(j0)]);           \
  acc[1][(j0)]   = MFMA(a1, B0, acc[1][(j0)]);           \
  acc[2][(j0)]   = MFMA(a2, B0, acc[2][(j0)]);           \
  acc[3][(j0)]   = MFMA(a3, B0, acc[3][(j0)]);           \
  acc[0][(j0)+1] = MFMA(a0, B1, acc[0][(j0)+1]);         \
  acc[1][(j0)+1] = MFMA(a1, B1, acc[1][(j0)+1]);         \
  acc[2][(j0)+1] = MFMA(a2, B1, acc[2][(j0)+1]);         \
  acc[3][(j0)+1] = MFMA(a3, B1, acc[3][(j0)+1]);         \
  __builtin_amdgcn_s_setprio(0);

#define LD(buf, off) (*(const f16x8*)((buf) + (off)))

__global__ __launch_bounds__(256, 2) void gemm_logits_k(
    const _Float16* __restrict__ Ah, const _Float16* __restrict__ Wh,
    const float* __restrict__ bias, float* __restrict__ C) {
  __shared__ uint4 lds4[3072];  // 48 KiB
  char* lds = (char*)lds4;
  const int tid = threadIdx.x;
  const int lane = tid & 63;
  const int wid = tid >> 6;          // 0..3
  const int wm = wid >> 1;           // 0..1 (M)
  const int wn = wid & 1;            // 0..1 (N)

  // XCD-aware bijective swizzle: 2048 blocks, 8 XCDs, 256 per XCD.
  const int bid = blockIdx.x;
  const int wgid = (bid & 7) * 256 + (bid >> 3);
  const int bm = wgid >> 2, bn = wgid & 3;   // 512 M-tiles x 4 N-tiles
  const int row0 = bm * 128, col0 = bn * 256;

  // Staging sources (inverse of the super-row swizzle). A: 2 chunks; B: 4 chunks.
  const _Float16* aSrc[2];
  const _Float16* bSrc[4];
#pragma unroll
  for (int q = 0; q < 2; ++q) {
    int p = q * 4096 + tid * 16;      // byte offset in A region (8KB)
    int srow = p >> 7;                // 0..63
    int s = (p >> 4) & 7;             // physical slot
    int sig = s ^ (srow & 7);         // logical slot
    int row = 2 * srow + (sig >> 2);
    aSrc[q] = Ah + ((size_t)(row0 + row) * 1024 + (size_t)(sig & 3) * 8);
  }
#pragma unroll
  for (int q = 0; q < 4; ++q) {
    int p = q * 4096 + tid * 16;      // byte offset in B region (16KB)
    int srow = p >> 7;                // 0..127
    int s = (p >> 4) & 7;
    int sig = s ^ (srow & 7);
    int row = 2 * srow + (sig >> 2);
    bSrc[q] = Wh + ((size_t)(col0 + row) * 1024 + (size_t)(sig & 3) * 8);
  }

  // Fragment read offsets. 16x16x32 A-op: lane -> row (lane&15), k-chunk u=lane>>4.
  const int u = lane >> 4;             // 0..3
  const int hr = (lane & 15) >> 1;     // srow low bits 0..7
  const int ls = u + 4 * (lane & 1);   // logical slot
  const int aoff = (wm * 32 + hr) * 128 + ((ls ^ hr) * 16);           // + fi*1024
  const int boff = 8192 + (wn * 64 + hr) * 128 + ((ls ^ hr) * 16);    // + fj*1024

  f32x4 acc[4][8] = {};

  // Prologue: tile 0 -> buf0, tile 1 -> buf1; vmcnt(6) -> tile 0 resident.
  char* buf0 = lds;
  char* buf1 = lds + 24576;
  GL2_A(buf0, 0)
  GL4_B(buf0, 0)
  GL2_A(buf1, 32)
  GL4_B(buf1, 32)
  ASM_VMCNT(6);
  BARRIER();

#pragma unroll 1
  for (int t = 0; t < 32; ++t) {
    char* ldsb = lds + (t & 1) * 24576;
    const int tt = (t + 2 < 32) ? t + 2 : 31;   // dummy tail reload keeps vmcnt cadence
    const size_t kof = (size_t)tt * 32;

    // 12 ds_reads: A (4) then B (8)
    f16x8 a0 = LD(ldsb, aoff + 0 * 1024);
    f16x8 a1 = LD(ldsb, aoff + 1 * 1024);
    f16x8 a2 = LD(ldsb, aoff + 2 * 1024);
    f16x8 a3 = LD(ldsb, aoff + 3 * 1024);
    f16x8 b0 = LD(ldsb, boff + 0 * 1024);
    f16x8 b1 = LD(ldsb, boff + 1 * 1024);
    f16x8 b2 = LD(ldsb, boff + 2 * 1024);
    f16x8 b3 = LD(ldsb, boff + 3 * 1024);
    f16x8 b4 = LD(ldsb, boff + 4 * 1024);
    f16x8 b5 = LD(ldsb, boff + 5 * 1024);
    f16x8 b6 = LD(ldsb, boff + 6 * 1024);
    f16x8 b7 = LD(ldsb, boff + 7 * 1024);
    ASM_LGKM(6);               // A + b0,b1 resident
    MCL(0, b0, b1)
    ASM_LGKM(4);               // b2,b3
    MCL(2, b2, b3)
    ASM_LGKM(2);               // b4,b5
    MCL(4, b4, b5)
    ASM_LGKM(0);               // all reads of ldsb done
    BARRIER();                 // every wave done reading -> safe to overwrite
    GL2_A(ldsb, kof)           // stage tile t+2 (6 loads)
    GL4_B(ldsb, kof)
    MCL(6, b6, b7)
    ASM_VMCNT(6);              // tile t+1's 6 loads landed (t+2's 6 in flight)
    BARRIER();
  }
  ASM_VMCNT(0);    // drain tail dummy loads

  // Epilogue: C[i,j] = acc + bias[j].  C/D: col=lane&15, row=(lane>>4)*4+q.
#pragma unroll
  for (int fj = 0; fj < 8; ++fj) {
    int c = col0 + wn * 128 + fj * 16 + (lane & 15);
    float bj = bias[c];
#pragma unroll
    for (int fi = 0; fi < 4; ++fi) {
      int r = row0 + wm * 64 + fi * 16 + u * 4;
#pragma unroll
      for (int q = 0; q < 4; ++q)
        C[(size_t)(r + q) * 1024 + c] = acc[fi][fj][q] + bj;
    }
  }
}

// ---------------- Kernel 4: fused softmax + gating + loss accumulation ----------------
__global__ __launch_bounds__(256) void softmax_loss_k(const float* __restrict__ logits,
                                                      const _Float16* __restrict__ hi,
                                                      float* __restrict__ out) {
  const int b = blockIdx.x;            // 0..1023
  const int tid = threadIdx.x, lane = tid & 63, wid = tid >> 6;
  __shared__ float red[8];
  float4 wprev = make_float4(1.f, 1.f, 1.f, 1.f);
  float4 lacc  = make_float4(0.f, 0.f, 0.f, 0.f);

  size_t base = (size_t)b * 1024;      // row (t=0, b)
  float4 x = ((const float4*)(logits + base))[tid];
  f16x4  h = ((const f16x4*)(hi + base))[tid];

#pragma unroll 1
  for (int t = 0; t < 64; ++t) {
    float4 se;
    se.x = (float)h[0];
    se.y = (float)h[1];
    se.z = (float)h[2];
    se.w = (float)h[3];
    lacc.x += wprev.x * se.x;
    lacc.y += wprev.y * se.y;
    lacc.z += wprev.z * se.z;
    lacc.w += wprev.w * se.w;

    int tn = (t + 1 < 64) ? t + 1 : t;
    size_t nbase = ((size_t)tn * 1024 + (size_t)b) * 1024;
    float4 xn = ((const float4*)(logits + nbase))[tid];
    f16x4  hn = ((const f16x4*)(hi + nbase))[tid];

    float m = fmaxf(fmaxf(x.x, x.y), fmaxf(x.z, x.w));
#pragma unroll
    for (int o = 32; o >= 1; o >>= 1) m = fmaxf(m, __shfl_xor(m, o, 64));
    if (lane == 0) red[wid] = m;
    __syncthreads();
    m = fmaxf(fmaxf(red[0], red[1]), fmaxf(red[2], red[3]));
    float e0 = __expf(x.x - m), e1 = __expf(x.y - m), e2 = __expf(x.z - m), e3 = __expf(x.w - m);
    float s = (e0 + e1) + (e2 + e3);
#pragma unroll
    for (int o = 32; o >= 1; o >>= 1) s += __shfl_xor(s, o, 64);
    if (lane == 0) red[4 + wid] = s;
    __syncthreads();
    s = (red[4] + red[5]) + (red[6] + red[7]);
    float inv = 1.0f / s;

    wprev.x = se.x * e0 * inv;
    wprev.y = se.y * e1 * inv;
    wprev.z = se.z * e2 * inv;
    wprev.w = se.w * e3 * inv;

    x = xn; h = hn;
  }
  ((float4*)(out + (size_t)b * 1024))[tid] = lacc;
}

extern "C" void kernel_launch(void* const* d_in, const int* in_sizes, int n_in,
                              void* d_out, int out_size, void* d_ws, size_t ws_size,
                              hipStream_t stream) {
  const float* pred = (const float*)d_in[0];
  const float* tru  = (const float*)d_in[1];
  const float* W    = (const float*)d_in[2];
  const float* bias = (const float*)d_in[3];
  float* out = (float*)d_out;

  char* ws = (char*)d_ws;
  _Float16* se_hi  = (_Float16*)(ws);                    // 128 MB
  float*    logits = (float*)   (ws + 134217728ull);     // 256 MB
  _Float16* W_hi   = (_Float16*)(ws + 402653184ull);     // 2 MB

  se_split_k<<<2048, 256, 0, stream>>>(pred, tru, se_hi);
  w_split_k<<<1024, 256, 0, stream>>>(W, W_hi);
  gemm_logits_k<<<2048, 256, 0, stream>>>(se_hi, W_hi, bias, logits);
  softmax_loss_k<<<1024, 256, 0, stream>>>(logits, se_hi, out);
}